// Round 6
// baseline (418.271 us; speedup 1.0000x reference)
//
#include <hip/hip_runtime.h>
#include <hip/hip_bf16.h>

typedef __hip_bfloat16 bf16;
typedef __attribute__((ext_vector_type(8))) short short8;
typedef __attribute__((ext_vector_type(4))) float float4v;

#define N_NODES 100000
#define M_PAD   100096        // 782 * 128
#define N_EDGES 1600000
#define D 128
#define K_CAT 384
#define NBIN 392              // 392 bins x 256 nodes >= 100000
#define BIN_CAP 4608          // E[4096] + 8 sigma
#define CHUNK 4096            // edges per phase-A block
#define NSLICE 8
#define SLICE_F 16
#define PLANE ((size_t)M_PAD * SLICE_F)   // elems per slice plane

__device__ __forceinline__ float b2f(bf16 v) { return __bfloat162float(v); }
__device__ __forceinline__ bf16 f2b(float v) { return __float2bfloat16(v); }
__device__ __forceinline__ float us2f(unsigned short u) {
    unsigned int x = ((unsigned int)u) << 16;
    return __uint_as_float(x);
}
__device__ __forceinline__ unsigned int pack2(float a, float b) {
    return (unsigned int)__bfloat16_as_ushort(f2b(a)) |
           ((unsigned int)__bfloat16_as_ushort(f2b(b)) << 16);
}

// ---- build combined TRANSPOSED weights (bf16): WcatT[o][k]
// k<128: W0-W2 ; 128..255: W1 ; 256..383: 2*W2   (diag_w = 0, Tx2 = 2*spmm(Tx1) - x)
__global__ void prep_w_kernel(const float* __restrict__ w, const float* __restrict__ bias,
                              bf16* __restrict__ wT, float* __restrict__ biasf) {
    int i = blockIdx.x * blockDim.x + threadIdx.x;
    if (i < D * K_CAT) {
        int o = i / K_CAT, k = i % K_CAT;
        float v;
        if (k < 128) {
            v = w[k * D + o] - w[2 * 16384 + k * D + o];
        } else if (k < 256) {
            v = w[16384 + (k - 128) * D + o];
        } else {
            v = 2.0f * w[2 * 16384 + (k - 256) * D + o];
        }
        wT[i] = f2b(v);
    }
    if (i < D) biasf[i] = bias[i];
}

// ---- x (fp32 row-major) -> xbT (bf16, slice-major [slice][M_PAD][16])
// block = 32 nodes x 8 slices; thread (p = tid>>5, nloc = tid&31) reads 64B of
// row nb+nloc (block collectively reads each row exactly once), writes 32B into
// plane p at node-contiguous addresses (coalesced across the 32 threads of p).
__global__ __launch_bounds__(256) void convx_kernel(const float* __restrict__ x,
                                                    bf16* __restrict__ xbT) {
    int tid = threadIdx.x;
    int p = tid >> 5, nloc = tid & 31;
    int n = blockIdx.x * 32 + nloc;
    bf16* dst = xbT + p * PLANE + (size_t)n * SLICE_F;
    if (n < N_NODES) {
        const float4* row = (const float4*)(x + (size_t)n * D + p * SLICE_F);
        float4 v0 = row[0], v1 = row[1], v2 = row[2], v3 = row[3];
        uint4 o0, o1;
        o0.x = pack2(v0.x, v0.y); o0.y = pack2(v0.z, v0.w);
        o0.z = pack2(v1.x, v1.y); o0.w = pack2(v1.z, v1.w);
        o1.x = pack2(v2.x, v2.y); o1.y = pack2(v2.z, v2.w);
        o1.z = pack2(v3.x, v3.y); o1.w = pack2(v3.z, v3.w);
        ((uint4*)dst)[0] = o0;
        ((uint4*)dst)[1] = o1;
    } else {
        uint4 z = {0, 0, 0, 0};
        ((uint4*)dst)[0] = z;
        ((uint4*)dst)[1] = z;
    }
}

// ---- Phase A: counting-sort binning of edges by dst-bin (d>>8) and src-bin (s>>8).
// Per block: LDS histograms, ONE global atomic per non-empty bin (~306K total),
// then scatter compact records. d-record = (s<<8)|(d&255) u32; s-record = u8.
__global__ __launch_bounds__(256) void phaseA_kernel(const int* __restrict__ src,
                                                     const int* __restrict__ dst,
                                                     int* __restrict__ gCursD,
                                                     int* __restrict__ gCursS,
                                                     unsigned int* __restrict__ gBinD,
                                                     unsigned char* __restrict__ gBinS) {
    __shared__ int histD[NBIN], histS[NBIN], cursD[NBIN], cursS[NBIN];
    int tid = threadIdx.x;
    for (int t = tid; t < NBIN; t += 256) { histD[t] = 0; histS[t] = 0; }
    __syncthreads();
    int e0 = blockIdx.x * CHUNK;
    for (int i = tid; i < CHUNK; i += 256) {
        int e = e0 + i;
        if (e >= N_EDGES) break;
        int s = src[e], d = dst[e];
        if (s == d) continue;           // self loops have ew = 0
        atomicAdd(&histD[d >> 8], 1);
        atomicAdd(&histS[s >> 8], 1);
    }
    __syncthreads();
    for (int t = tid; t < NBIN; t += 256) {
        cursD[t] = (histD[t] > 0) ? atomicAdd(&gCursD[t], histD[t]) : 0;
        cursS[t] = (histS[t] > 0) ? atomicAdd(&gCursS[t], histS[t]) : 0;
    }
    __syncthreads();
    for (int i = tid; i < CHUNK; i += 256) {
        int e = e0 + i;
        if (e >= N_EDGES) break;
        int s = src[e], d = dst[e];
        if (s == d) continue;
        int bd = d >> 8, bs = s >> 8;
        int sd = atomicAdd(&cursD[bd], 1);
        if (sd < BIN_CAP) gBinD[(size_t)bd * BIN_CAP + sd] = ((unsigned int)s << 8) | (unsigned int)(d & 255);
        int ss = atomicAdd(&cursS[bs], 1);
        if (ss < BIN_CAP) gBinS[(size_t)bs * BIN_CAP + ss] = (unsigned char)(s & 255);
    }
}

// ---- Phase B: block exclusively owns one 256-node bin -> zero global atomics.
// Blocks [0,NBIN): CSR build (count -> LDS scan -> place recS, cnt, recOff).
// Blocks [NBIN,2*NBIN): out-degree histogram -> dis = rsqrt(deg).
__global__ __launch_bounds__(256) void phaseB_kernel(const int* __restrict__ gCursD,
                                                     const int* __restrict__ gCursS,
                                                     const unsigned int* __restrict__ gBinD,
                                                     const unsigned char* __restrict__ gBinS,
                                                     int* __restrict__ cnt,
                                                     int* __restrict__ recOff,
                                                     float* __restrict__ dis,
                                                     unsigned int* __restrict__ recS) {
    __shared__ int hist[256], scan[256], curs[256];
    int tid = threadIdx.x;
    int b = blockIdx.x;
    hist[tid] = 0;
    __syncthreads();
    if (b < NBIN) {
        int count = min(gCursD[b], BIN_CAP);
        const unsigned int* rec = gBinD + (size_t)b * BIN_CAP;
        for (int j = tid; j < count; j += 256) atomicAdd(&hist[rec[j] & 255], 1);
        __syncthreads();
        int v = hist[tid];
        scan[tid] = v;
        __syncthreads();
        for (int o = 1; o < 256; o <<= 1) {
            int add = (tid >= o) ? scan[tid - o] : 0;
            __syncthreads();
            scan[tid] += add;
            __syncthreads();
        }
        int excl = scan[tid] - v;
        curs[tid] = excl;
        __syncthreads();
        unsigned int* outp = recS + (size_t)b * BIN_CAP;
        for (int j = tid; j < count; j += 256) {
            unsigned int r = rec[j];
            int slot = atomicAdd(&curs[r & 255], 1);   // LDS atomic
            outp[slot] = r;
        }
        int n = (b << 8) + tid;
        if (n < N_NODES) { cnt[n] = v; recOff[n] = b * BIN_CAP + excl; }
    } else {
        int bb = b - NBIN;
        int count = min(gCursS[bb], BIN_CAP);
        const unsigned char* rec = gBinS + (size_t)bb * BIN_CAP;
        for (int j = tid; j < count; j += 256) atomicAdd(&hist[rec[j]], 1);
        __syncthreads();
        int n = (bb << 8) + tid;
        if (n < N_NODES) {
            int c = hist[tid];
            dis[n] = (c > 0) ? rsqrtf((float)c) : 0.0f;
        }
    }
}

// ---- fill recW = -dis[s]*dis[d] (needs complete dis -> separate kernel)
__global__ __launch_bounds__(256) void prew_kernel(const int* __restrict__ gCursD,
                                                   const unsigned int* __restrict__ recS,
                                                   const float* __restrict__ dis,
                                                   float* __restrict__ recW) {
    int b = blockIdx.x;
    int count = min(gCursD[b], BIN_CAP);
    const unsigned int* rp = recS + (size_t)b * BIN_CAP;
    float* wp = recW + (size_t)b * BIN_CAP;
    for (int j = threadIdx.x; j < count; j += 256) {
        unsigned int r = rp[j];
        int s = (int)(r >> 8);
        int dn = (b << 8) + (int)(r & 255);
        wp[j] = -dis[s] * dis[dn];
    }
}

// ---- feature-sliced gather SpMM: outT[p][n][:] = sum_j recW[j] * inT[p][src_j][:]
// blockIdx&7 = slice p -> round-robin XCD mapping keeps plane p (3.2 MB) resident
// in ONE XCD's 4 MB L2 (locality heuristic only; correctness mapping-independent).
// wave = 8 nodes x 8 lanes (2 feats/lane); unroll-4 for MLP.
__global__ __launch_bounds__(256) void spmm_slice_kernel(const bf16* __restrict__ inT,
                                                         const int* __restrict__ recOff,
                                                         const int* __restrict__ cnt,
                                                         const unsigned int* __restrict__ recS,
                                                         const float* __restrict__ recW,
                                                         bf16* __restrict__ outT) {
    int p = blockIdx.x & 7;
    int g = blockIdx.x >> 3;
    int wv = threadIdx.x >> 6, lane = threadIdx.x & 63;
    int nsub = lane >> 3, fl = lane & 7;
    int n = g * 32 + wv * 8 + nsub;
    const bf16* plane = inT + p * PLANE;
    int c = 0, off = 0;
    if (n < N_NODES) { c = cnt[n]; off = recOff[n]; }
    float a0 = 0.0f, a1 = 0.0f;
    int j = 0;
    for (; j + 4 <= c; j += 4) {
        unsigned int r0 = recS[off + j + 0], r1 = recS[off + j + 1];
        unsigned int r2 = recS[off + j + 2], r3 = recS[off + j + 3];
        float w0 = recW[off + j + 0], w1 = recW[off + j + 1];
        float w2 = recW[off + j + 2], w3 = recW[off + j + 3];
        unsigned int u0 = *(const unsigned int*)(plane + (size_t)(r0 >> 8) * SLICE_F + fl * 2);
        unsigned int u1 = *(const unsigned int*)(plane + (size_t)(r1 >> 8) * SLICE_F + fl * 2);
        unsigned int u2 = *(const unsigned int*)(plane + (size_t)(r2 >> 8) * SLICE_F + fl * 2);
        unsigned int u3 = *(const unsigned int*)(plane + (size_t)(r3 >> 8) * SLICE_F + fl * 2);
        a0 += w0 * us2f((unsigned short)(u0 & 0xffff)) + w1 * us2f((unsigned short)(u1 & 0xffff))
            + w2 * us2f((unsigned short)(u2 & 0xffff)) + w3 * us2f((unsigned short)(u3 & 0xffff));
        a1 += w0 * us2f((unsigned short)(u0 >> 16)) + w1 * us2f((unsigned short)(u1 >> 16))
            + w2 * us2f((unsigned short)(u2 >> 16)) + w3 * us2f((unsigned short)(u3 >> 16));
    }
    for (; j < c; j++) {
        unsigned int r = recS[off + j];
        float w = recW[off + j];
        unsigned int u = *(const unsigned int*)(plane + (size_t)(r >> 8) * SLICE_F + fl * 2);
        a0 += w * us2f((unsigned short)(u & 0xffff));
        a1 += w * us2f((unsigned short)(u >> 16));
    }
    *(unsigned int*)(outT + p * PLANE + (size_t)n * SLICE_F + fl * 2) = pack2(a0, a1);
}

// ---- MFMA bf16 GEMM: out[m][n] = sum_k A[m][k] * W[k][n] + bias[n]
// A = [ x (fp32, cvt on the fly) | tx1T | agg2T ] (K=384); tx1/agg2 read from
// slice-major planes (contiguous 4KB panels). B via WcatT[o][k].
#define AS_STRIDE 40   // 32 + 8 pad elems -> 80B row stride, 2-way LDS conflicts only
__global__ __launch_bounds__(256) void gemm_kernel(const float* __restrict__ x,
                                                   const bf16* __restrict__ tx1T,
                                                   const bf16* __restrict__ agg2T,
                                                   const bf16* __restrict__ wT,
                                                   const float* __restrict__ biasf,
                                                   float* __restrict__ out) {
    __shared__ bf16 As[128 * AS_STRIDE];
    __shared__ bf16 Bs[128 * AS_STRIDE];

    int tid = threadIdx.x;
    int nb = blockIdx.x * 128;
    int w = tid >> 6;          // wave 0..3 -> rows [32w, 32w+32)
    int lane = tid & 63;
    int lq = lane >> 4;        // quad 0..3
    int lr = lane & 15;

    float4v acc[2][8];
#pragma unroll
    for (int i = 0; i < 2; i++)
#pragma unroll
        for (int j = 0; j < 8; j++) acc[i][j] = (float4v)0.0f;

    for (int kc = 0; kc < 12; kc++) {
        int kbase = kc * 32;
        // ---- stage A tile (128 rows x 32 k, bf16)
        if (kc < 4) {
            // source: x fp32, convert to bf16. 1024 chunks of 4 floats.
#pragma unroll
            for (int t = 0; t < 4; t++) {
                int c = tid + t * 256;
                int row = c >> 3;
                int off = (c & 7) * 4;
                int gr = nb + row;
                if (gr > N_NODES - 1) gr = N_NODES - 1;   // clamp: pad rows discarded later
                float4 v = *(const float4*)(x + (size_t)gr * D + kbase + off);
                uint2 pk;
                pk.x = pack2(v.x, v.y);
                pk.y = pack2(v.z, v.w);
                *(uint2*)(As + row * AS_STRIDE + off) = pk;
            }
        } else {
            // source: slice planes. K-block kc covers slices 2m, 2m+1 of its tensor.
            const bf16* base = (kc < 8) ? tx1T : agg2T;
            int m2 = (kc & 3) * 2;
#pragma unroll
            for (int sr = 0; sr < 2; sr++) {
                const bf16* chunkp = base + (size_t)(m2 + sr) * PLANE + (size_t)nb * SLICE_F;
                uint4 v = *(const uint4*)(chunkp + tid * 8);
                int row = tid >> 1;
                int col = sr * 16 + (tid & 1) * 8;
                *(uint4*)(As + row * AS_STRIDE + col) = v;
            }
        }
        // ---- stage B tile: WcatT rows (o = 0..127) x 32 k
#pragma unroll
        for (int t = 0; t < 2; t++) {
            int c = tid + t * 256;
            int row = c >> 2;
            int off = (c & 3) * 8;
            uint4 v = *(const uint4*)(wT + (size_t)row * K_CAT + kbase + off);
            *(uint4*)(Bs + row * AS_STRIDE + off) = v;
        }
        __syncthreads();

        // ---- fragments + MFMA
        short8 af[2], bfr[8];
#pragma unroll
        for (int i = 0; i < 2; i++)
            af[i] = *(const short8*)(As + (w * 32 + i * 16 + lr) * AS_STRIDE + lq * 8);
#pragma unroll
        for (int j = 0; j < 8; j++)
            bfr[j] = *(const short8*)(Bs + (j * 16 + lr) * AS_STRIDE + lq * 8);
#pragma unroll
        for (int i = 0; i < 2; i++)
#pragma unroll
            for (int j = 0; j < 8; j++)
                acc[i][j] = __builtin_amdgcn_mfma_f32_16x16x32_bf16(af[i], bfr[j], acc[i][j], 0, 0, 0);
        __syncthreads();
    }

    // ---- epilogue: C/D layout col = lane&15, row = (lane>>4)*4 + reg
#pragma unroll
    for (int i = 0; i < 2; i++) {
        int rowb = nb + w * 32 + i * 16 + lq * 4;
#pragma unroll
        for (int j = 0; j < 8; j++) {
            int col = j * 16 + lr;
            float bv = biasf[col];
#pragma unroll
            for (int r = 0; r < 4; r++) {
                int row = rowb + r;
                if (row < N_NODES) out[(size_t)row * D + col] = acc[i][j][r] + bv;
            }
        }
    }
}

extern "C" void kernel_launch(void* const* d_in, const int* in_sizes, int n_in,
                              void* d_out, int out_size, void* d_ws, size_t ws_size,
                              hipStream_t stream) {
    const float* x    = (const float*)d_in[0];
    const int*   ei   = (const int*)d_in[1];
    const float* w    = (const float*)d_in[2];
    const float* bias = (const float*)d_in[3];
    float* out = (float*)d_out;

    char* p = (char*)d_ws;
    int*   cnt    = (int*)p;            p += (size_t)N_NODES * 4;
    float* dis    = (float*)p;          p += (size_t)N_NODES * 4;
    int*   recOff = (int*)p;            p += (size_t)N_NODES * 4;
    int*   gCurs  = (int*)p;            p += (size_t)2 * NBIN * 4;
    unsigned int* recS = (unsigned int*)p;  p += (size_t)NBIN * BIN_CAP * 4;
    float* recW   = (float*)p;          p += (size_t)NBIN * BIN_CAP * 4;
    bf16*  R1     = (bf16*)p;           p += PLANE * NSLICE * 2;   // xbT, later agg2T
    bf16*  R2     = (bf16*)p;           p += PLANE * NSLICE * 2;   // gBinD+gBinS, later tx1T
    bf16*  wT     = (bf16*)p;           p += (size_t)D * K_CAT * 2;
    float* biasf  = (float*)p;          p += (size_t)D * 4;
    // total ~67.0 MB (<= proven ws in prior rounds)

    int* gCursD = gCurs;
    int* gCursS = gCurs + NBIN;
    // aliases: gBin region lives in R2 (dead once phaseB consumes it; spmm1 then
    // writes tx1T there). xbT lives in R1 (dead after spmm1; spmm2 writes agg2T).
    unsigned int*  gBinD = (unsigned int*)R2;                            // 7.23 MB
    unsigned char* gBinS = (unsigned char*)(gBinD + (size_t)NBIN * BIN_CAP);  // 1.81 MB
    bf16* xbT   = R1;
    bf16* tx1T  = R2;
    bf16* agg2T = R1;

    hipMemsetAsync(gCurs, 0, (size_t)2 * NBIN * 4, stream);

    prep_w_kernel<<<(D * K_CAT + 255) / 256, 256, 0, stream>>>(w, bias, wT, biasf);
    convx_kernel<<<M_PAD / 32, 256, 0, stream>>>(x, xbT);
    phaseA_kernel<<<(N_EDGES + CHUNK - 1) / CHUNK, 256, 0, stream>>>(ei, ei + N_EDGES,
                                                                     gCursD, gCursS, gBinD, gBinS);
    phaseB_kernel<<<2 * NBIN, 256, 0, stream>>>(gCursD, gCursS, gBinD, gBinS,
                                                cnt, recOff, dis, recS);
    prew_kernel<<<NBIN, 256, 0, stream>>>(gCursD, recS, dis, recW);
    // pass 1: tx1T = spmm(xbT)   (writes over gBin region — dead now)
    spmm_slice_kernel<<<(M_PAD / 32) * 8, 256, 0, stream>>>(xbT, recOff, cnt, recS, recW, tx1T);
    // pass 2: agg2T = spmm(tx1T) (writes over xbT — dead now)
    spmm_slice_kernel<<<(M_PAD / 32) * 8, 256, 0, stream>>>(tx1T, recOff, cnt, recS, recW, agg2T);
    gemm_kernel<<<M_PAD / 128, 256, 0, stream>>>(x, tx1T, agg2T, wT, biasf, out);
}